// Round 6
// baseline (3596.989 us; speedup 1.0000x reference)
//
#include <hip/hip_runtime.h>

// VQ quantisation: x [32,256,64,64] f32, codebook [1024,256] f32.
// Output = codebook[argmin_j ||x - e_j||^2], [B,C,H,W] f32.
//
// CRITICAL SEMANTICS (learned round 3): the harness reference computes
// distances in FLOAT32: d_j = fl32(fl32(x_sq - 2*dot_j) + e_sq_j), with
// x_sq ~ 256 so ulp(d) ~ 3e-5 >> inter-code spread. ~0.4% of rows have
// top-2 QUANTIZED to the same f32 value; argmin then picks the FIRST index.
// We must replicate the f32-quantized argmin (first-index ties), not the
// exact one. Coarse f32 screen (gap < DELTA flags row) + full quantized
// re-score of flagged rows with correctly-rounded f32 X, E, dot.

#define Bb 32
#define Cc 256
#define Hh 64
#define Ww 64
#define Kn 1024
#define Dd 256
#define NROWS (Bb * Hh * Ww)   // 131072
#define DELTA 2e-4f            // tie window 2*ulp(~256)=6.1e-5 + coarse err; 3x safety

// ---------------- kernel 0: esq32[j] = fl32( f64-sum of fl32(e_c^2) ) ----------------
__global__ void esq_kernel(const float* __restrict__ cb, float* __restrict__ esq32) {
    int j = blockIdx.x * blockDim.x + threadIdx.x;
    if (j >= Kn) return;
    const float4* row = reinterpret_cast<const float4*>(cb + j * Dd);
    double s = 0.0;
#pragma unroll 8
    for (int i = 0; i < Dd / 4; ++i) {
        float4 v = row[i];
        float a = v.x * v.x, b = v.y * v.y, c = v.z * v.z, d = v.w * v.w;  // fl32 squares
        s += (double)a; s += (double)b; s += (double)c; s += (double)d;
    }
    esq32[j] = (float)s;  // correctly rounded
}

// ---------------- kernel 1: coarse fp32 screen with top-2 gap tracking ----------------
// One block per (b,h): 64 rows. LDS: x_tile[256][64] + cb_tile[256][64] (128 KB dynamic).
// 256 threads = 16 (tx: 4 w each) x 16 (ty: 4 j each). 16 codebook tiles of 64 entries.
__global__ __launch_bounds__(256) void coarse_kernel(
    const float* __restrict__ x, const float* __restrict__ cb,
    const float* __restrict__ esq32,
    int* __restrict__ idxbuf, int* __restrict__ flagbuf) {
    extern __shared__ float smem[];
    float* x_lds = smem;              // [c][w]  256*64
    float* cb_lds = smem + 256 * 64;  // [c][jl] 256*64

    const int bh = blockIdx.x;        // b*64 + h
    const int b = bh >> 6;
    const int h = bh & 63;
    const int n0 = bh * 64;
    const int tid = threadIdx.x;
    const int tx = tid & 15;          // w group
    const int ty = tid >> 4;          // j group

    // ---- stage x tile: x[b, c, h, 0..63] -> x_lds[c][w] ----
    const float4* xf4 = reinterpret_cast<const float4*>(x);
#pragma unroll
    for (int i = 0; i < 16; ++i) {
        int f = tid + 256 * i;        // 4096 float4s
        int c = f >> 4;
        int w4 = f & 15;
        float4 v = xf4[(size_t)(b * Cc + c) * 1024 + h * 16 + w4];
        *reinterpret_cast<float4*>(&x_lds[c * 64 + w4 * 4]) = v;
    }

    float m1[4], m2[4];
    int i1[4];
#pragma unroll
    for (int ww = 0; ww < 4; ++ww) { m1[ww] = 3.0e38f; m2[ww] = 3.0e38f; i1[ww] = 0; }

    const float4* cbf4 = reinterpret_cast<const float4*>(cb);

    for (int jt = 0; jt < 16; ++jt) {
        const int j0 = jt * 64;
        __syncthreads();
        // ---- stage cb tile transposed: cb[j0+jl][c] -> cb_lds[c][jl] ----
#pragma unroll
        for (int i = 0; i < 16; ++i) {
            int f = tid + 256 * i;    // 4096 float4s
            int jl = f & 63;
            int c4 = f >> 6;
            float4 v = cbf4[(size_t)(j0 + jl) * 64 + c4];
            int c = c4 * 4;
            cb_lds[(c + 0) * 64 + jl] = v.x;
            cb_lds[(c + 1) * 64 + jl] = v.y;
            cb_lds[(c + 2) * 64 + jl] = v.z;
            cb_lds[(c + 3) * 64 + jl] = v.w;
        }
        __syncthreads();

        float acc[4][4];
#pragma unroll
        for (int a = 0; a < 4; ++a)
#pragma unroll
            for (int q = 0; q < 4; ++q) acc[a][q] = 0.f;

#pragma unroll 4
        for (int c = 0; c < Dd; ++c) {
            float4 xv = *reinterpret_cast<const float4*>(&x_lds[c * 64 + tx * 4]);
            float4 ev = *reinterpret_cast<const float4*>(&cb_lds[c * 64 + ty * 4]);
            const float xs[4] = {xv.x, xv.y, xv.z, xv.w};
            const float es[4] = {ev.x, ev.y, ev.z, ev.w};
#pragma unroll
            for (int a = 0; a < 4; ++a)
#pragma unroll
                for (int q = 0; q < 4; ++q) acc[a][q] += xs[a] * es[q];
        }

        // g = e_sq - 2*dot (x_sq row-constant; dropped for the SCREEN only)
#pragma unroll
        for (int q = 0; q < 4; ++q) {
            int j = j0 + ty * 4 + q;
            float e = esq32[j];
#pragma unroll
            for (int a = 0; a < 4; ++a) {
                float g = e - 2.0f * acc[a][q];
                if (g < m1[a]) { m2[a] = m1[a]; m1[a] = g; i1[a] = j; }
                else if (g < m2[a]) { m2[a] = g; }
            }
        }
    }

    // ---- merge 16 ty-partials per row via LDS ----
    __syncthreads();
    float* pm1 = smem;                      // [64][16]
    float* pm2 = smem + 64 * 16;            // [64][16]
    int* pi1 = reinterpret_cast<int*>(smem + 2 * 64 * 16);  // [64][16]
#pragma unroll
    for (int a = 0; a < 4; ++a) {
        int w = tx * 4 + a;
        pm1[w * 16 + ty] = m1[a];
        pm2[w * 16 + ty] = m2[a];
        pi1[w * 16 + ty] = i1[a];
    }
    __syncthreads();
    if (tid < 64) {
        int w = tid;
        float M1 = 3.0e38f, M2 = 3.0e38f;
        int I1 = 0;
#pragma unroll
        for (int t = 0; t < 16; ++t) {
            float a1 = pm1[w * 16 + t];
            float a2 = pm2[w * 16 + t];
            int ai = pi1[w * 16 + t];
            if (a1 < M1) { M2 = fminf(M1, a2); M1 = a1; I1 = ai; }
            else { M2 = fminf(M2, a1); }
        }
        int row = n0 + w;
        idxbuf[row] = I1;
        flagbuf[row] = (M2 - M1 < DELTA) ? 1 : 0;
    }
}

// ---------------- kernel 2: full f32-QUANTIZED re-score of flagged rows ----------------
// One wave per flagged row. s_j = fl32(fl32(X - 2*R_j) + E_j) with X, R_j correctly
// rounded from f64; argmin with first-index tie-break (matches np.argmin).
__global__ __launch_bounds__(256) void refine_kernel(
    const float* __restrict__ x, const float* __restrict__ cb,
    const float* __restrict__ esq32, const int* __restrict__ flagbuf,
    int* __restrict__ idxbuf) {
    __shared__ float xs_lds[4][256];       // per-wave row staging (wave-local use only)
    const int lane = threadIdx.x & 63;
    const int wid = threadIdx.x >> 6;
    const int gw = (blockIdx.x * blockDim.x + threadIdx.x) >> 6;
    const int nw = (gridDim.x * blockDim.x) >> 6;
    float* myx = xs_lds[wid];
    const float4* cbf4 = reinterpret_cast<const float4*>(cb);

    for (int row = gw; row < NROWS; row += nw) {
        if (!flagbuf[row]) continue;       // wave-uniform branch; no __syncthreads used
        const int b = row >> 12;
        const int h = (row >> 6) & 63;
        const int w = row & 63;
        const float* xrow = x + (size_t)b * Cc * 4096 + h * 64 + w;  // channel c at +c*4096

        float xr[4];
#pragma unroll
        for (int t = 0; t < 4; ++t) xr[t] = xrow[(size_t)(t * 64 + lane) * 4096];
        // stage row channels to LDS (same-wave RAW; compiler inserts lgkmcnt waits)
#pragma unroll
        for (int t = 0; t < 4; ++t) myx[t * 64 + lane] = xr[t];

        // X = fl32(f64-sum of fl32 squares); xor-butterfly => bit-identical on all lanes
        double xs = 0.0;
#pragma unroll
        for (int t = 0; t < 4; ++t) { float q = xr[t] * xr[t]; xs += (double)q; }
#pragma unroll
        for (int off = 1; off < 64; off <<= 1) xs += __shfl_xor(xs, off);
        const float X = (float)xs;

        float best = 3.0e38f;
        int bi = Kn;
#pragma unroll 1
        for (int t = 0; t < 16; ++t) {
            const int j = t * 64 + lane;
            const float4* crow = cbf4 + (size_t)j * 64;
            double acc = 0.0;
            for (int c4 = 0; c4 < 64; ++c4) {
                float4 e = crow[c4];                                          // contiguous 16B
                float4 xv = *reinterpret_cast<const float4*>(&myx[c4 * 4]);   // broadcast read
                acc = fma((double)xv.x, (double)e.x, acc);
                acc = fma((double)xv.y, (double)e.y, acc);
                acc = fma((double)xv.z, (double)e.z, acc);
                acc = fma((double)xv.w, (double)e.w, acc);
            }
            float R = (float)acc;            // correctly-rounded f32 dot
            float t2 = X - 2.0f * R;         // single f32 rounding (2*R exact)
            float s = t2 + esq32[j];         // single f32 rounding
            if (s < best) { best = s; bi = j; }  // t ascending => j ascending, strict <
        }
        // wave argmin with first-index tie-break
        for (int off = 32; off > 0; off >>= 1) {
            float ob = __shfl_down(best, off);
            int oi = __shfl_down(bi, off);
            if (ob < best || (ob == best && oi < bi)) { best = ob; bi = oi; }
        }
        if (lane == 0) idxbuf[row] = bi;
    }
}

// ---------------- kernel 3: gather codebook -> NCHW output (4c x 4w register transpose) ----------------
__global__ __launch_bounds__(256) void scatter_kernel(
    const float* __restrict__ cb, const int* __restrict__ idxbuf,
    float* __restrict__ out) {
    int it = blockIdx.x * 256 + threadIdx.x;  // 2,097,152 items
    int wg = it & 15;          // w group (4 w)
    int cg = (it >> 4) & 63;   // c group (4 c)
    int bh = it >> 10;         // b*64 + h
    int b = bh >> 6;
    int h = bh & 63;
    int n = bh * 64 + wg * 4;
    int4 id = *reinterpret_cast<const int4*>(&idxbuf[n]);
    const int c0 = cg * 4;
    float4 r0 = *reinterpret_cast<const float4*>(&cb[(size_t)id.x * Dd + c0]);
    float4 r1 = *reinterpret_cast<const float4*>(&cb[(size_t)id.y * Dd + c0]);
    float4 r2 = *reinterpret_cast<const float4*>(&cb[(size_t)id.z * Dd + c0]);
    float4 r3 = *reinterpret_cast<const float4*>(&cb[(size_t)id.w * Dd + c0]);
    float* o = out + ((size_t)(b * Cc + c0)) * 4096 + h * 64 + wg * 4;
    *reinterpret_cast<float4*>(o + 0 * 4096) = make_float4(r0.x, r1.x, r2.x, r3.x);
    *reinterpret_cast<float4*>(o + 1 * 4096) = make_float4(r0.y, r1.y, r2.y, r3.y);
    *reinterpret_cast<float4*>(o + 2 * 4096) = make_float4(r0.z, r1.z, r2.z, r3.z);
    *reinterpret_cast<float4*>(o + 3 * 4096) = make_float4(r0.w, r1.w, r2.w, r3.w);
}

extern "C" void kernel_launch(void* const* d_in, const int* in_sizes, int n_in,
                              void* d_out, int out_size, void* d_ws, size_t ws_size,
                              hipStream_t stream) {
    const float* x = (const float*)d_in[0];        // [32,256,64,64]
    const float* cb = (const float*)d_in[1];       // [1024,256]
    float* out = (float*)d_out;                    // [32,256,64,64]

    char* ws = (char*)d_ws;
    float* esq32 = (float*)ws;                     // 1024 * 4 = 4 KB
    int* idxbuf = (int*)(ws + 16384);              // 131072 * 4 = 512 KB
    int* flagbuf = (int*)(ws + 16384 + 524288);    // 131072 * 4 = 512 KB

    (void)hipFuncSetAttribute((const void*)coarse_kernel,
                              hipFuncAttributeMaxDynamicSharedMemorySize, 128 * 1024);

    esq_kernel<<<4, 256, 0, stream>>>(cb, esq32);
    coarse_kernel<<<NROWS / 64, 256, 128 * 1024, stream>>>(x, cb, esq32, idxbuf, flagbuf);
    refine_kernel<<<512, 256, 0, stream>>>(x, cb, esq32, flagbuf, idxbuf);
    scatter_kernel<<<(Bb * Cc * Hh * Ww / 16) / 256, 256, 0, stream>>>(cb, idxbuf, out);
}